// Round 5
// baseline (82.837 us; speedup 1.0000x reference)
//
#include <hip/hip_runtime.h>
#include <hip/hip_bf16.h>

#define BB 8
#define CC 64
#define NN 4096
#define KT 64          // keys per tile
#define QW 32          // queries per wave
#define WAVES 2
#define QB (QW*WAVES)  // 64 queries per block
#define VROW 72        // padded V^T row: 64 bf16 data + 8 pad (144 B)
#define VTILE (2*32*VROW)   // shorts per key-tile = 4608 (9216 B)
#define LOG2E 1.44269504088896340736f

typedef short bf16x8 __attribute__((ext_vector_type(8)));
typedef float f32x16 __attribute__((ext_vector_type(16)));
typedef unsigned int uint4v __attribute__((ext_vector_type(4)));

__device__ __forceinline__ unsigned cvt_pk_bf16(float lo, float hi) {
    unsigned r;
    asm("v_cvt_pk_bf16_f32 %0, %1, %2" : "=v"(r) : "v"(lo), "v"(hi));
    return r;
}

__device__ __forceinline__ void glds16(const void* g, void* l) {
    __builtin_amdgcn_global_load_lds(
        (const __attribute__((address_space(1))) unsigned int*)g,
        (__attribute__((address_space(3))) unsigned int*)l, 16, 0, 0);
}

// ---------------------------------------------------------------------------
// Kernel 1: QKV projection, 5 output-groups x 128 position-tiles = 640 blocks.
// grp 0: q (scaled by log2e) + k -> [b][n][8] bf16; grp 1-4: 16 V channels
// each -> padded V^T subtile layout (mirrors attn LDS for linear glds copy).
// ---------------------------------------------------------------------------
__global__ __launch_bounds__(256) void qkv_kernel(
    const float* __restrict__ X,
    const float* __restrict__ Wq, const float* __restrict__ bq,
    const float* __restrict__ Wk, const float* __restrict__ bk,
    const float* __restrict__ Wv, const float* __restrict__ bv,
    unsigned short* __restrict__ qw, unsigned short* __restrict__ kw,
    unsigned short* __restrict__ vw)
{
    __shared__ float wbuf[64 * 16];
    __shared__ float bsh[16];

    const int t = threadIdx.x;
    const int grp = blockIdx.x % 5;
    const int tile = blockIdx.x / 5;
    const int b = tile >> 4;
    const int n = ((tile & 15) << 8) + t;

    if (grp == 0) {
        for (int i = t; i < 512; i += 256) {
            int o = i >> 6, c = i & 63;
            wbuf[c * 16 + o]     = Wq[i];
            wbuf[c * 16 + 8 + o] = Wk[i];
        }
        if (t < 8) { bsh[t] = bq[t]; bsh[8 + t] = bk[t]; }
    } else {
        const int cbase = (grp - 1) * 16;
        for (int i = t; i < 1024; i += 256) {
            int o = i >> 6, c = i & 63;
            wbuf[c * 16 + o] = Wv[(cbase + o) * 64 + c];
        }
        if (t < 16) bsh[t] = bv[cbase + t];
    }
    __syncthreads();

    float a[16];
    #pragma unroll
    for (int j = 0; j < 16; j++) a[j] = bsh[j];

    const float* xp = X + (size_t)b * CC * NN + n;
    for (int c = 0; c < 64; c++) {
        float xc = xp[(size_t)c * NN];
        const float4* w4 = (const float4*)&wbuf[c * 16];
        float4 w0 = w4[0], w1 = w4[1], w2 = w4[2], w3 = w4[3];
        a[0]  += w0.x * xc; a[1]  += w0.y * xc; a[2]  += w0.z * xc; a[3]  += w0.w * xc;
        a[4]  += w1.x * xc; a[5]  += w1.y * xc; a[6]  += w1.z * xc; a[7]  += w1.w * xc;
        a[8]  += w2.x * xc; a[9]  += w2.y * xc; a[10] += w2.z * xc; a[11] += w2.w * xc;
        a[12] += w3.x * xc; a[13] += w3.y * xc; a[14] += w3.z * xc; a[15] += w3.w * xc;
    }

    if (grp == 0) {
        alignas(16) __hip_bfloat16 qb8[8], kb8[8];
        #pragma unroll
        for (int d = 0; d < 8; d++) {
            qb8[d] = __float2bfloat16(a[d] * LOG2E);
            kb8[d] = __float2bfloat16(a[8 + d]);
        }
        const size_t g = (size_t)b * NN + n;
        *(int4*)(qw + g * 8) = *(const int4*)qb8;
        *(int4*)(kw + g * 8) = *(const int4*)kb8;
    } else {
        const int cbase = (grp - 1) * 16;
        unsigned short* vb = vw + ((size_t)(b * (NN / KT) + (n >> 6))) * VTILE + (n & 63);
        #pragma unroll
        for (int j = 0; j < 16; j++) {
            int cg = cbase + j;
            vb[(cg >> 5) * (32 * VROW) + (cg & 31) * VROW] =
                __builtin_bit_cast(unsigned short, __float2bfloat16(a[j]));
        }
    }
}

// ---------------------------------------------------------------------------
// Kernel 2: MFMA flash attention. 128-thread blocks (2 waves x 32 queries).
//   S^T = mfma_32x32x16(K, Q^T) x2 ; P = exp2(S) ; out^T += mfma(V^T, P^T) x8
// Partials in bf16 (pout), denominators fp32 (pl). Grid 2048 (KS=4),
// XCD-swizzled for K/V L2 locality.
// ---------------------------------------------------------------------------
template<int KS, bool FUSE>
__global__ __launch_bounds__(128) void attn_kernel(
    const unsigned short* __restrict__ qw, const unsigned short* __restrict__ kw,
    const unsigned short* __restrict__ vw,
    unsigned short* __restrict__ pout, float* __restrict__ pl,
    const float* __restrict__ X, const float* __restrict__ gamma,
    float* __restrict__ out)
{
    __shared__ alignas(16) short klds[2][KT * 8 + 8];
    __shared__ alignas(16) short vlds[2][VTILE];

    const int t = threadIdx.x;
    const int w = t >> 6, lane = t & 63;
    const int h = lane >> 5, q = lane & 31;

    // bijective XCD swizzle (grid = 64*8*KS, divisible by 8)
    const int nwg = gridDim.x;
    const int cpx = nwg >> 3;
    const int bid = (blockIdx.x % 8) * cpx + (blockIdx.x >> 3);

    const int qtile = bid & 63;
    const int b = (bid >> 6) & 7;
    const int ks = bid >> 9;

    const int qbase = qtile * QB + w * QW;

    if (t < 16) klds[t >> 3][KT * 8 + (t & 7)] = 0;

    bf16x8 qf = {};
    if (h == 0) qf = *(const bf16x8*)(qw + ((size_t)b * NN + qbase + q) * 8);

    f32x16 acc0 = {}, acc1 = {};
    float lsum = 0.f;

    const int NT = NN / KS / KT;
    const int tile0 = ks * NT;

    auto stage = [&](int buf, int tile) {
        const char* kbase = (const char*)(kw + ((size_t)b * NN + (size_t)tile * KT) * 8);
        if (w == 0) glds16(kbase + lane * 16, &klds[buf][0]);
        const char* vbase = (const char*)(vw + ((size_t)(b * (NN / KT) + tile)) * VTILE);
        for (int c2 = w; c2 < 9; c2 += WAVES)
            glds16(vbase + c2 * 1024 + (size_t)lane * 16, (char*)&vlds[buf][0] + c2 * 1024);
    };

    stage(0, tile0);
    __syncthreads();

    int cur = 0;
    for (int it = 0; it < NT; ++it) {
        if (it + 1 < NT) stage(cur ^ 1, tile0 + it + 1);

        // ---- QK^T (swapped), two 32-key halves ----
        const short* kl = &klds[cur][0];
        bf16x8 kf0 = *(const bf16x8*)(kl + (h == 0 ? q * 8        : KT * 8));
        bf16x8 kf1 = *(const bf16x8*)(kl + (h == 0 ? (32 + q) * 8 : KT * 8));
        f32x16 s0 = __builtin_amdgcn_mfma_f32_32x32x16_bf16(kf0, qf, (f32x16){}, 0, 0, 0);
        f32x16 s1 = __builtin_amdgcn_mfma_f32_32x32x16_bf16(kf1, qf, (f32x16){}, 0, 0, 0);

        // ---- softmax numerators: exp2 (Q pre-scaled by log2e) ----
        float pa[16], pb[16];
        #pragma unroll
        for (int r = 0; r < 16; ++r) pa[r] = __builtin_exp2f(s0[r]);
        #pragma unroll
        for (int r = 0; r < 16; ++r) pb[r] = __builtin_exp2f(s1[r]);
        // pairwise-tree partial sums (short dependency chains)
        float t0 = 0.f, t1 = 0.f, t2 = 0.f, t3 = 0.f;
        #pragma unroll
        for (int r = 0; r < 4; ++r) {
            t0 += pa[r];  t1 += pa[4 + r];  t2 += pa[8 + r];  t3 += pa[12 + r];
            t0 += pb[r];  t1 += pb[4 + r];  t2 += pb[8 + r];  t3 += pb[12 + r];
        }
        lsum += (t0 + t1) + (t2 + t3);

        unsigned pk[16];
        #pragma unroll
        for (int j = 0; j < 8; ++j) {
            pk[j]     = cvt_pk_bf16(pa[2 * j], pa[2 * j + 1]);
            pk[8 + j] = cvt_pk_bf16(pb[2 * j], pb[2 * j + 1]);
        }

        // ---- PV: out^T += V^T · P^T ----
        const short* vl = &vlds[cur][0];
        __builtin_amdgcn_s_setprio(1);
        #pragma unroll
        for (int g = 0; g < 4; ++g) {
            const unsigned* pkg = &pk[4 * g];
            auto ra = __builtin_amdgcn_permlane32_swap(pkg[2], pkg[0], false, false);
            auto rb = __builtin_amdgcn_permlane32_swap(pkg[3], pkg[1], false, false);
            uint4v bu = { ra[1], rb[1], ra[0], rb[0] };
            bf16x8 pf = __builtin_bit_cast(bf16x8, bu);
            bf16x8 v0 = *(const bf16x8*)(vl + 0 * 32 * VROW + q * VROW + g * 16 + h * 8);
            acc0 = __builtin_amdgcn_mfma_f32_32x32x16_bf16(v0, pf, acc0, 0, 0, 0);
            bf16x8 v1 = *(const bf16x8*)(vl + 1 * 32 * VROW + q * VROW + g * 16 + h * 8);
            acc1 = __builtin_amdgcn_mfma_f32_32x32x16_bf16(v1, pf, acc1, 0, 0, 0);
        }
        __builtin_amdgcn_s_setprio(0);
        __syncthreads();
        cur ^= 1;
    }

    auto rs = __builtin_amdgcn_permlane32_swap(__builtin_bit_cast(unsigned, lsum),
                                               __builtin_bit_cast(unsigned, lsum), false, false);
    float ltot = __builtin_bit_cast(float, rs[0]) + __builtin_bit_cast(float, rs[1]);

    const int n = qbase + q;
    if (FUSE) {
        const float gm = gamma[0];
        const float inv = 1.f / ltot;
        #pragma unroll
        for (int ct = 0; ct < 2; ++ct) {
            const f32x16& a = ct ? acc1 : acc0;
            #pragma unroll
            for (int r = 0; r < 16; ++r) {
                int c = ct * 32 + (r & 3) + 8 * (r >> 2) + 4 * h;
                size_t idx = ((size_t)(b * CC + c)) * NN + n;
                out[idx] = X[idx] + gm * a[r] * inv;
            }
        }
    } else {
        unsigned short* po = pout + (size_t)ks * BB * CC * NN;
        #pragma unroll
        for (int ct = 0; ct < 2; ++ct) {
            const f32x16& a = ct ? acc1 : acc0;
            #pragma unroll
            for (int r = 0; r < 16; ++r) {
                int c = ct * 32 + (r & 3) + 8 * (r >> 2) + 4 * h;
                po[((size_t)(b * CC + c)) * NN + n] =
                    __builtin_bit_cast(unsigned short, __float2bfloat16(a[r]));
            }
        }
        if (h == 0) pl[((size_t)(ks * BB + b)) * NN + n] = ltot;
    }
}

// ---------------------------------------------------------------------------
// Kernel 3: combine KS key-splits (bf16 partials) + epilogue.
// ---------------------------------------------------------------------------
template<int KS>
__global__ __launch_bounds__(256) void combine_kernel(
    const unsigned short* __restrict__ pout, const float* __restrict__ pl,
    const float* __restrict__ X, const float* __restrict__ gamma,
    float* __restrict__ out)
{
    const int idx = blockIdx.x * 256 + threadIdx.x;   // B*C*N/4
    const int n4 = idx & 1023;
    const int c  = (idx >> 10) & 63;
    const int b  = idx >> 16;
    const int n0 = n4 * 4;
    const float gm = gamma[0];
    const size_t base = ((size_t)(b * CC + c)) * NN + n0;

    float4 s = make_float4(0.f, 0.f, 0.f, 0.f);
    float4 L = make_float4(0.f, 0.f, 0.f, 0.f);
    #pragma unroll
    for (int ks = 0; ks < KS; ++ks) {
        ushort4 sv = *(const ushort4*)(pout + (size_t)ks * BB * CC * NN + base);
        float4 lv = *(const float4*)(pl + ((size_t)(ks * BB + b)) * NN + n0);
        s.x += __bfloat162float(__builtin_bit_cast(__hip_bfloat16, sv.x));
        s.y += __bfloat162float(__builtin_bit_cast(__hip_bfloat16, sv.y));
        s.z += __bfloat162float(__builtin_bit_cast(__hip_bfloat16, sv.z));
        s.w += __bfloat162float(__builtin_bit_cast(__hip_bfloat16, sv.w));
        L.x += lv.x; L.y += lv.y; L.z += lv.z; L.w += lv.w;
    }
    float4 x = *(const float4*)(X + base);
    float4 o;
    o.x = x.x + gm * s.x / L.x;
    o.y = x.y + gm * s.y / L.y;
    o.z = x.z + gm * s.z / L.z;
    o.w = x.w + gm * s.w / L.w;
    *(float4*)(out + base) = o;
}

// ---------------------------------------------------------------------------
extern "C" void kernel_launch(void* const* d_in, const int* in_sizes, int n_in,
                              void* d_out, int out_size, void* d_ws, size_t ws_size,
                              hipStream_t stream) {
    const float* X  = (const float*)d_in[0];
    const float* Wq = (const float*)d_in[1];
    const float* bq = (const float*)d_in[2];
    const float* Wk = (const float*)d_in[3];
    const float* bk = (const float*)d_in[4];
    const float* Wv = (const float*)d_in[5];
    const float* bv = (const float*)d_in[6];
    const float* gm = (const float*)d_in[7];
    float* out = (float*)d_out;

    unsigned short* qw = (unsigned short*)d_ws;                      // B*N*8 bf16
    unsigned short* kw = qw + (size_t)BB * NN * 8;                   // B*N*8 bf16
    unsigned short* vw = kw + (size_t)BB * NN * 8;                   // B*(N/64)*4608 bf16
    unsigned short* pout = vw + (size_t)BB * (NN / KT) * VTILE;      // KS*B*C*N bf16
    float* pl = (float*)(pout + (size_t)4 * BB * CC * NN);           // KS*B*N f32

    const size_t qkv_bytes = ((size_t)BB * NN * 8 * 2) * 2 + (size_t)BB * (NN / KT) * VTILE * 2;
    const size_t need4 = qkv_bytes + (size_t)4 * BB * CC * NN * 2 + (size_t)4 * BB * NN * 4;
    const size_t need2 = qkv_bytes + (size_t)2 * BB * CC * NN * 2 + (size_t)2 * BB * NN * 4;

    qkv_kernel<<<dim3(640), dim3(256), 0, stream>>>(X, Wq, bq, Wk, bk, Wv, bv, qw, kw, vw);

    if (ws_size >= need4) {
        attn_kernel<4, false><<<dim3(2048), dim3(128), 0, stream>>>(
            qw, kw, vw, pout, pl, X, gm, out);
        combine_kernel<4><<<dim3((BB * CC * NN / 4) / 256), dim3(256), 0, stream>>>(
            pout, pl, X, gm, out);
    } else if (ws_size >= need2) {
        float* pl2 = (float*)(pout + (size_t)2 * BB * CC * NN);
        attn_kernel<2, false><<<dim3(1024), dim3(128), 0, stream>>>(
            qw, kw, vw, pout, pl2, X, gm, out);
        combine_kernel<2><<<dim3((BB * CC * NN / 4) / 256), dim3(256), 0, stream>>>(
            pout, pl2, X, gm, out);
    } else {
        attn_kernel<1, true><<<dim3(512), dim3(128), 0, stream>>>(
            qw, kw, vw, nullptr, nullptr, X, gm, out);
    }
}

// Round 6
// 58.494 us; speedup vs baseline: 1.4162x; 1.4162x over previous
//
#include <hip/hip_runtime.h>
#include <hip/hip_bf16.h>

#define BB 8
#define CC 64
#define NN 4096
#define LOG2E 1.44269504088896340736f

typedef short bf16x8 __attribute__((ext_vector_type(8)));
typedef float f32x16 __attribute__((ext_vector_type(16)));
typedef unsigned int uint4v __attribute__((ext_vector_type(4)));

__device__ __forceinline__ unsigned cvt_pk_bf16(float lo, float hi) {
    unsigned r;
    asm("v_cvt_pk_bf16_f32 %0, %1, %2" : "=v"(r) : "v"(lo), "v"(hi));
    return r;
}

__device__ __forceinline__ float fast_exp2(float x) {
#if __has_builtin(__builtin_amdgcn_exp2f)
    return __builtin_amdgcn_exp2f(x);
#else
    return __builtin_exp2f(x);
#endif
}

// Workspace fragment layouts (all bf16 shorts):
//  qw   [b][n][8]                                      (B*N*8)
//  kfrag[b][tile32][lane64][8]  lane<32: K[key][d], lane>=32: zeros  (B*128*512)
//  vfrag[b][tile64][slab8][lane64][8]                  (B*64*4096)
//    slab = g*2+ct ; lane=(q,h) holds V^T[ch=ct*32+q][key=tile*64+g*16+h*8+i]

// ---------------------------------------------------------------------------
// Kernel 1: QKV projection, 5 groups x 128 position-tiles = 640 blocks.
// grp 0: q (x log2e) + k -> qw/kfrag.  grp 1-4: 16 V channels -> vfrag via
// LDS transpose (coalesced fragment writes).
// ---------------------------------------------------------------------------
__global__ __launch_bounds__(256) void qkv_kernel(
    const float* __restrict__ X,
    const float* __restrict__ Wq, const float* __restrict__ bq,
    const float* __restrict__ Wk, const float* __restrict__ bk,
    const float* __restrict__ Wv, const float* __restrict__ bv,
    unsigned short* __restrict__ qw, unsigned short* __restrict__ kfrag,
    unsigned short* __restrict__ vfrag)
{
    __shared__ float wbuf[64 * 16];
    __shared__ float bsh[16];
    __shared__ short vsh[16][264];   // [channel][position], padded row

    const int t = threadIdx.x;
    const int grp = blockIdx.x % 5;
    const int tile = blockIdx.x / 5;
    const int b = tile >> 4;
    const int nb = (tile & 15) << 8;      // block's base position
    const int n = nb + t;

    if (grp == 0) {
        for (int i = t; i < 512; i += 256) {
            int o = i >> 6, c = i & 63;
            wbuf[c * 16 + o]     = Wq[i];
            wbuf[c * 16 + 8 + o] = Wk[i];
        }
        if (t < 8) { bsh[t] = bq[t]; bsh[8 + t] = bk[t]; }
    } else {
        const int cbase = (grp - 1) * 16;
        for (int i = t; i < 1024; i += 256) {
            int o = i >> 6, c = i & 63;
            wbuf[c * 16 + o] = Wv[(cbase + o) * 64 + c];
        }
        if (t < 16) bsh[t] = bv[cbase + t];
    }
    __syncthreads();

    float a[16];
    #pragma unroll
    for (int j = 0; j < 16; j++) a[j] = bsh[j];

    const float* xp = X + (size_t)b * CC * NN + n;
    for (int c = 0; c < 64; c++) {
        float xc = xp[(size_t)c * NN];
        const float4* w4 = (const float4*)&wbuf[c * 16];
        float4 w0 = w4[0], w1 = w4[1], w2 = w4[2], w3 = w4[3];
        a[0]  += w0.x * xc; a[1]  += w0.y * xc; a[2]  += w0.z * xc; a[3]  += w0.w * xc;
        a[4]  += w1.x * xc; a[5]  += w1.y * xc; a[6]  += w1.z * xc; a[7]  += w1.w * xc;
        a[8]  += w2.x * xc; a[9]  += w2.y * xc; a[10] += w2.z * xc; a[11] += w2.w * xc;
        a[12] += w3.x * xc; a[13] += w3.y * xc; a[14] += w3.z * xc; a[15] += w3.w * xc;
    }

    if (grp == 0) {
        alignas(16) __hip_bfloat16 qb8[8], kb8[8];
        #pragma unroll
        for (int d = 0; d < 8; d++) {
            qb8[d] = __float2bfloat16(a[d] * LOG2E);
            kb8[d] = __float2bfloat16(a[8 + d]);
        }
        const size_t g = (size_t)b * NN + n;
        *(int4*)(qw + g * 8) = *(const int4*)qb8;
        // K fragment: tile32 = n>>5, row = n&31 (data), row 32+(n&31) = zeros
        size_t kf = ((size_t)b * 128 + (n >> 5)) * 512;
        *(int4*)(kfrag + kf + (size_t)(n & 31) * 8) = *(const int4*)kb8;
        *(int4*)(kfrag + kf + (size_t)(32 + (n & 31)) * 8) = make_int4(0, 0, 0, 0);
    } else {
        const int cbase = (grp - 1) * 16;
        const int qb0 = cbase & 31, ct = cbase >> 5;
        #pragma unroll
        for (int j = 0; j < 16; j++)
            vsh[j][t] = __builtin_bit_cast(short, __float2bfloat16(a[j]));
        __syncthreads();
        // write out 512 rows (16B each); thread handles rows 2t, 2t+1
        #pragma unroll
        for (int rr = 0; rr < 2; ++rr) {
            int r = 2 * t + rr;
            int qq = r & 15, hh = (r >> 4) & 1, gg = (r >> 5) & 3, tau = r >> 7;
            int n0 = tau * 64 + gg * 16 + hh * 8;
            int4 val = *(const int4*)&vsh[qq][n0];
            int gtile = (nb >> 6) + tau;
            size_t dst = ((size_t)(b * 64 + gtile)) * 4096
                       + (size_t)(gg * 2 + ct) * 512
                       + (size_t)(32 * hh + qb0 + qq) * 8;
            *(int4*)(vfrag + dst) = val;
        }
    }
}

// ---------------------------------------------------------------------------
// Kernel 2: MFMA flash attention — NO LDS, NO barriers. All K/V fragments
// loaded directly from L2-resident workspace in MFMA fragment order
// (coalesced 16B/lane). Each wave owns 64 queries (2 sub-tiles A,B).
// Grid = 16 qtiles x 8 b x KS, XCD-swizzled so each XCD keeps one (ks, b-set)
// working set (~640KB) in its private L2.
// ---------------------------------------------------------------------------
template<int KS, bool FUSE>
__global__ __launch_bounds__(256, 2) void attn_kernel(
    const unsigned short* __restrict__ qw,
    const unsigned short* __restrict__ kfrag,
    const unsigned short* __restrict__ vfrag,
    unsigned short* __restrict__ pout, float* __restrict__ pl,
    const float* __restrict__ X, const float* __restrict__ gamma,
    float* __restrict__ out)
{
    const int t = threadIdx.x;
    const int w = t >> 6, lane = t & 63;
    const int h = lane >> 5, q = lane & 31;

    const int nwg = gridDim.x;
    const int cpx = nwg >> 3;
    const int bid = (blockIdx.x & 7) * cpx + (blockIdx.x >> 3);

    const int qtile = bid & 15;
    const int b = (bid >> 4) & 7;
    const int ks = bid >> 7;

    const int qbase = qtile * 256 + w * 64;

    bf16x8 qfA = {}, qfB = {};
    if (h == 0) {
        qfA = *(const bf16x8*)(qw + ((size_t)b * NN + qbase + q) * 8);
        qfB = *(const bf16x8*)(qw + ((size_t)b * NN + qbase + 32 + q) * 8);
    }

    f32x16 accA0 = {}, accA1 = {}, accB0 = {}, accB1 = {};
    float lsumA = 0.f, lsumB = 0.f;

    const int NT = NN / KS / 64;
    const int tile0 = ks * NT;
    const unsigned short* kb = kfrag + (size_t)b * 65536;
    const unsigned short* vb = vfrag + (size_t)b * 262144;

    for (int it = 0; it < NT; ++it) {
        const int gt = tile0 + it;
        const unsigned short* kp = kb + (size_t)gt * 1024 + (size_t)lane * 8;
        bf16x8 kf0 = *(const bf16x8*)kp;
        bf16x8 kf1 = *(const bf16x8*)(kp + 512);

        f32x16 sA0 = __builtin_amdgcn_mfma_f32_32x32x16_bf16(kf0, qfA, (f32x16){}, 0, 0, 0);
        f32x16 sA1 = __builtin_amdgcn_mfma_f32_32x32x16_bf16(kf1, qfA, (f32x16){}, 0, 0, 0);
        f32x16 sB0 = __builtin_amdgcn_mfma_f32_32x32x16_bf16(kf0, qfB, (f32x16){}, 0, 0, 0);
        f32x16 sB1 = __builtin_amdgcn_mfma_f32_32x32x16_bf16(kf1, qfB, (f32x16){}, 0, 0, 0);

        unsigned pkA[16], pkB[16];
        {
            float pa[16], pb2[16];
            #pragma unroll
            for (int r = 0; r < 16; ++r) { pa[r] = fast_exp2(sA0[r]); pb2[r] = fast_exp2(sA1[r]); }
            float t0 = 0.f, t1 = 0.f, t2 = 0.f, t3 = 0.f;
            #pragma unroll
            for (int r = 0; r < 4; ++r) {
                t0 += pa[r]; t1 += pa[4 + r]; t2 += pa[8 + r]; t3 += pa[12 + r];
                t0 += pb2[r]; t1 += pb2[4 + r]; t2 += pb2[8 + r]; t3 += pb2[12 + r];
            }
            lsumA += (t0 + t1) + (t2 + t3);
            #pragma unroll
            for (int j = 0; j < 8; ++j) {
                pkA[j]     = cvt_pk_bf16(pa[2 * j], pa[2 * j + 1]);
                pkA[8 + j] = cvt_pk_bf16(pb2[2 * j], pb2[2 * j + 1]);
            }
            #pragma unroll
            for (int r = 0; r < 16; ++r) { pa[r] = fast_exp2(sB0[r]); pb2[r] = fast_exp2(sB1[r]); }
            t0 = t1 = t2 = t3 = 0.f;
            #pragma unroll
            for (int r = 0; r < 4; ++r) {
                t0 += pa[r]; t1 += pa[4 + r]; t2 += pa[8 + r]; t3 += pa[12 + r];
                t0 += pb2[r]; t1 += pb2[4 + r]; t2 += pb2[8 + r]; t3 += pb2[12 + r];
            }
            lsumB += (t0 + t1) + (t2 + t3);
            #pragma unroll
            for (int j = 0; j < 8; ++j) {
                pkB[j]     = cvt_pk_bf16(pa[2 * j], pa[2 * j + 1]);
                pkB[8 + j] = cvt_pk_bf16(pb2[2 * j], pb2[2 * j + 1]);
            }
        }

        const unsigned short* vp = vb + (size_t)gt * 4096 + (size_t)lane * 8;
        __builtin_amdgcn_s_setprio(1);
        #pragma unroll
        for (int g = 0; g < 4; ++g) {
            const unsigned* pga = &pkA[4 * g];
            auto ra = __builtin_amdgcn_permlane32_swap(pga[2], pga[0], false, false);
            auto rb = __builtin_amdgcn_permlane32_swap(pga[3], pga[1], false, false);
            uint4v bua = { ra[1], rb[1], ra[0], rb[0] };
            bf16x8 pfA = __builtin_bit_cast(bf16x8, bua);
            const unsigned* pgb = &pkB[4 * g];
            auto rc = __builtin_amdgcn_permlane32_swap(pgb[2], pgb[0], false, false);
            auto rd = __builtin_amdgcn_permlane32_swap(pgb[3], pgb[1], false, false);
            uint4v bub = { rc[1], rd[1], rc[0], rd[0] };
            bf16x8 pfB = __builtin_bit_cast(bf16x8, bub);

            bf16x8 v0 = *(const bf16x8*)(vp + (size_t)(g * 2) * 512);
            bf16x8 v1 = *(const bf16x8*)(vp + (size_t)(g * 2 + 1) * 512);
            accA0 = __builtin_amdgcn_mfma_f32_32x32x16_bf16(v0, pfA, accA0, 0, 0, 0);
            accA1 = __builtin_amdgcn_mfma_f32_32x32x16_bf16(v1, pfA, accA1, 0, 0, 0);
            accB0 = __builtin_amdgcn_mfma_f32_32x32x16_bf16(v0, pfB, accB0, 0, 0, 0);
            accB1 = __builtin_amdgcn_mfma_f32_32x32x16_bf16(v1, pfB, accB1, 0, 0, 0);
        }
        __builtin_amdgcn_s_setprio(0);
    }

    auto rsA = __builtin_amdgcn_permlane32_swap(__builtin_bit_cast(unsigned, lsumA),
                                                __builtin_bit_cast(unsigned, lsumA), false, false);
    float ltotA = __builtin_bit_cast(float, rsA[0]) + __builtin_bit_cast(float, rsA[1]);
    auto rsB = __builtin_amdgcn_permlane32_swap(__builtin_bit_cast(unsigned, lsumB),
                                                __builtin_bit_cast(unsigned, lsumB), false, false);
    float ltotB = __builtin_bit_cast(float, rsB[0]) + __builtin_bit_cast(float, rsB[1]);

    const float gm = FUSE ? gamma[0] : 0.f;

    #pragma unroll
    for (int sub = 0; sub < 2; ++sub) {
        const int n = qbase + sub * 32 + q;
        const float ltot = sub ? ltotB : ltotA;
        const f32x16& a0 = sub ? accB0 : accA0;
        const f32x16& a1 = sub ? accB1 : accA1;
        if (FUSE) {
            const float inv = 1.f / ltot;
            #pragma unroll
            for (int ct = 0; ct < 2; ++ct) {
                const f32x16& a = ct ? a1 : a0;
                #pragma unroll
                for (int r = 0; r < 16; ++r) {
                    int c = ct * 32 + (r & 3) + 8 * (r >> 2) + 4 * h;
                    size_t idx = ((size_t)(b * CC + c)) * NN + n;
                    out[idx] = X[idx] + gm * a[r] * inv;
                }
            }
        } else {
            unsigned short* po = pout + (size_t)ks * BB * CC * NN;
            #pragma unroll
            for (int ct = 0; ct < 2; ++ct) {
                const f32x16& a = ct ? a1 : a0;
                #pragma unroll
                for (int r = 0; r < 16; ++r) {
                    int c = ct * 32 + (r & 3) + 8 * (r >> 2) + 4 * h;
                    po[((size_t)(b * CC + c)) * NN + n] =
                        __builtin_bit_cast(unsigned short, __float2bfloat16(a[r]));
                }
            }
            if (h == 0) pl[((size_t)(ks * BB + b)) * NN + n] = ltot;
        }
    }
}

// ---------------------------------------------------------------------------
// Kernel 3: combine KS key-splits (bf16 partials) + epilogue.
// ---------------------------------------------------------------------------
template<int KS>
__global__ __launch_bounds__(256) void combine_kernel(
    const unsigned short* __restrict__ pout, const float* __restrict__ pl,
    const float* __restrict__ X, const float* __restrict__ gamma,
    float* __restrict__ out)
{
    const int idx = blockIdx.x * 256 + threadIdx.x;   // B*C*N/4
    const int n4 = idx & 1023;
    const int c  = (idx >> 10) & 63;
    const int b  = idx >> 16;
    const int n0 = n4 * 4;
    const float gm = gamma[0];
    const size_t base = ((size_t)(b * CC + c)) * NN + n0;

    float4 s = make_float4(0.f, 0.f, 0.f, 0.f);
    float4 L = make_float4(0.f, 0.f, 0.f, 0.f);
    #pragma unroll
    for (int ks = 0; ks < KS; ++ks) {
        ushort4 sv = *(const ushort4*)(pout + (size_t)ks * BB * CC * NN + base);
        float4 lv = *(const float4*)(pl + ((size_t)(ks * BB + b)) * NN + n0);
        s.x += __bfloat162float(__builtin_bit_cast(__hip_bfloat16, sv.x));
        s.y += __bfloat162float(__builtin_bit_cast(__hip_bfloat16, sv.y));
        s.z += __bfloat162float(__builtin_bit_cast(__hip_bfloat16, sv.z));
        s.w += __bfloat162float(__builtin_bit_cast(__hip_bfloat16, sv.w));
        L.x += lv.x; L.y += lv.y; L.z += lv.z; L.w += lv.w;
    }
    float4 x = *(const float4*)(X + base);
    float4 o;
    o.x = x.x + gm * s.x / L.x;
    o.y = x.y + gm * s.y / L.y;
    o.z = x.z + gm * s.z / L.z;
    o.w = x.w + gm * s.w / L.w;
    *(float4*)(out + base) = o;
}

// ---------------------------------------------------------------------------
extern "C" void kernel_launch(void* const* d_in, const int* in_sizes, int n_in,
                              void* d_out, int out_size, void* d_ws, size_t ws_size,
                              hipStream_t stream) {
    const float* X  = (const float*)d_in[0];
    const float* Wq = (const float*)d_in[1];
    const float* bq = (const float*)d_in[2];
    const float* Wk = (const float*)d_in[3];
    const float* bk = (const float*)d_in[4];
    const float* Wv = (const float*)d_in[5];
    const float* bv = (const float*)d_in[6];
    const float* gm = (const float*)d_in[7];
    float* out = (float*)d_out;

    unsigned short* qw    = (unsigned short*)d_ws;                 // B*N*8
    unsigned short* kfrag = qw + (size_t)BB * NN * 8;              // B*128*512
    unsigned short* vfrag = kfrag + (size_t)BB * 128 * 512;        // B*64*4096
    unsigned short* pout  = vfrag + (size_t)BB * 64 * 4096;        // KS*B*C*N
    float* pl = (float*)(pout + (size_t)4 * BB * CC * NN);         // KS*B*N

    const size_t qkv_bytes = ((size_t)BB * NN * 8 + (size_t)BB * 128 * 512
                            + (size_t)BB * 64 * 4096) * 2;
    const size_t need4 = qkv_bytes + (size_t)4 * BB * CC * NN * 2 + (size_t)4 * BB * NN * 4;
    const size_t need2 = qkv_bytes + (size_t)2 * BB * CC * NN * 2 + (size_t)2 * BB * NN * 4;

    qkv_kernel<<<dim3(640), dim3(256), 0, stream>>>(X, Wq, bq, Wk, bk, Wv, bv, qw, kfrag, vfrag);

    if (ws_size >= need4) {
        attn_kernel<4, false><<<dim3(512), dim3(256), 0, stream>>>(
            qw, kfrag, vfrag, pout, pl, X, gm, out);
        combine_kernel<4><<<dim3((BB * CC * NN / 4) / 256), dim3(256), 0, stream>>>(
            pout, pl, X, gm, out);
    } else if (ws_size >= need2) {
        float* pl2 = (float*)(pout + (size_t)2 * BB * CC * NN);
        attn_kernel<2, false><<<dim3(256), dim3(256), 0, stream>>>(
            qw, kfrag, vfrag, pout, pl2, X, gm, out);
        combine_kernel<2><<<dim3((BB * CC * NN / 4) / 256), dim3(256), 0, stream>>>(
            pout, pl2, X, gm, out);
    } else {
        attn_kernel<1, true><<<dim3(128), dim3(256), 0, stream>>>(
            qw, kfrag, vfrag, nullptr, nullptr, X, gm, out);
    }
}

// Round 7
// 51.513 us; speedup vs baseline: 1.6081x; 1.1355x over previous
//
#include <hip/hip_runtime.h>
#include <hip/hip_bf16.h>

#define BB 8
#define CC 64
#define NN 4096
#define LOG2E 1.44269504088896340736f

typedef short bf16x8 __attribute__((ext_vector_type(8)));
typedef float f32x16 __attribute__((ext_vector_type(16)));
typedef unsigned int uint4v __attribute__((ext_vector_type(4)));

__device__ __forceinline__ unsigned cvt_pk_bf16(float lo, float hi) {
    unsigned r;
    asm("v_cvt_pk_bf16_f32 %0, %1, %2" : "=v"(r) : "v"(lo), "v"(hi));
    return r;
}

__device__ __forceinline__ float fast_exp2(float x) {
#if __has_builtin(__builtin_amdgcn_exp2f)
    return __builtin_amdgcn_exp2f(x);
#else
    return __builtin_exp2f(x);
#endif
}

// Workspace fragment layouts (all bf16 shorts):
//  qw   [b][n][8]
//  kfrag[b][tile32][lane64][8]  lane<32: K[key][d], lane>=32: zeros
//  vfrag[b][tile64][slab8][lane64][8]  slab = g*2+ct;
//    lane=(q,h) holds V^T[ch=ct*32+q][key=tile*64+g*16+h*8+i]

// ---------------------------------------------------------------------------
// Kernel 1: QKV projection, 5 groups x 128 position-tiles = 640 blocks.
// ---------------------------------------------------------------------------
__global__ __launch_bounds__(256) void qkv_kernel(
    const float* __restrict__ X,
    const float* __restrict__ Wq, const float* __restrict__ bq,
    const float* __restrict__ Wk, const float* __restrict__ bk,
    const float* __restrict__ Wv, const float* __restrict__ bv,
    unsigned short* __restrict__ qw, unsigned short* __restrict__ kfrag,
    unsigned short* __restrict__ vfrag)
{
    __shared__ float wbuf[64 * 16];
    __shared__ float bsh[16];
    __shared__ short vsh[16][264];

    const int t = threadIdx.x;
    const int grp = blockIdx.x % 5;
    const int tile = blockIdx.x / 5;
    const int b = tile >> 4;
    const int nb = (tile & 15) << 8;
    const int n = nb + t;

    if (grp == 0) {
        for (int i = t; i < 512; i += 256) {
            int o = i >> 6, c = i & 63;
            wbuf[c * 16 + o]     = Wq[i];
            wbuf[c * 16 + 8 + o] = Wk[i];
        }
        if (t < 8) { bsh[t] = bq[t]; bsh[8 + t] = bk[t]; }
    } else {
        const int cbase = (grp - 1) * 16;
        for (int i = t; i < 1024; i += 256) {
            int o = i >> 6, c = i & 63;
            wbuf[c * 16 + o] = Wv[(cbase + o) * 64 + c];
        }
        if (t < 16) bsh[t] = bv[cbase + t];
    }
    __syncthreads();

    float a[16];
    #pragma unroll
    for (int j = 0; j < 16; j++) a[j] = bsh[j];

    const float* xp = X + (size_t)b * CC * NN + n;
    for (int c = 0; c < 64; c++) {
        float xc = xp[(size_t)c * NN];
        const float4* w4 = (const float4*)&wbuf[c * 16];
        float4 w0 = w4[0], w1 = w4[1], w2 = w4[2], w3 = w4[3];
        a[0]  += w0.x * xc; a[1]  += w0.y * xc; a[2]  += w0.z * xc; a[3]  += w0.w * xc;
        a[4]  += w1.x * xc; a[5]  += w1.y * xc; a[6]  += w1.z * xc; a[7]  += w1.w * xc;
        a[8]  += w2.x * xc; a[9]  += w2.y * xc; a[10] += w2.z * xc; a[11] += w2.w * xc;
        a[12] += w3.x * xc; a[13] += w3.y * xc; a[14] += w3.z * xc; a[15] += w3.w * xc;
    }

    if (grp == 0) {
        alignas(16) __hip_bfloat16 qb8[8], kb8[8];
        #pragma unroll
        for (int d = 0; d < 8; d++) {
            qb8[d] = __float2bfloat16(a[d] * LOG2E);
            kb8[d] = __float2bfloat16(a[8 + d]);
        }
        const size_t g = (size_t)b * NN + n;
        *(int4*)(qw + g * 8) = *(const int4*)qb8;
        size_t kf = ((size_t)b * 128 + (n >> 5)) * 512;
        *(int4*)(kfrag + kf + (size_t)(n & 31) * 8) = *(const int4*)kb8;
        *(int4*)(kfrag + kf + (size_t)(32 + (n & 31)) * 8) = make_int4(0, 0, 0, 0);
    } else {
        const int cbase = (grp - 1) * 16;
        const int qb0 = cbase & 31, ct = cbase >> 5;
        #pragma unroll
        for (int j = 0; j < 16; j++)
            vsh[j][t] = __builtin_bit_cast(short, __float2bfloat16(a[j]));
        __syncthreads();
        #pragma unroll
        for (int rr = 0; rr < 2; ++rr) {
            int r = 2 * t + rr;
            int qq = r & 15, hh = (r >> 4) & 1, gg = (r >> 5) & 3, tau = r >> 7;
            int n0 = tau * 64 + gg * 16 + hh * 8;
            int4 val = *(const int4*)&vsh[qq][n0];
            int gtile = (nb >> 6) + tau;
            size_t dst = ((size_t)(b * 64 + gtile)) * 4096
                       + (size_t)(gg * 2 + ct) * 512
                       + (size_t)(32 * hh + qb0 + qq) * 8;
            *(int4*)(vfrag + dst) = val;
        }
    }
}

// ---------------------------------------------------------------------------
// Kernel 2: MFMA flash attention — no LDS, no barriers, lean register
// schedule. Two 32-key phases per 64-key tile: only one s-pair (32 VGPR)
// and one pk-set (16 VGPR) live at a time; K prefetched one tile ahead;
// all 8 V fragments issued at tile top for latency distance.
// ---------------------------------------------------------------------------
template<int KS, bool FUSE>
__global__ __launch_bounds__(256, 2) void attn_kernel(
    const unsigned short* __restrict__ qw,
    const unsigned short* __restrict__ kfrag,
    const unsigned short* __restrict__ vfrag,
    unsigned short* __restrict__ pout, float* __restrict__ pl,
    const float* __restrict__ X, const float* __restrict__ gamma,
    float* __restrict__ out)
{
    const int t = threadIdx.x;
    const int w = t >> 6, lane = t & 63;
    const int h = lane >> 5, q = lane & 31;

    const int nwg = gridDim.x;
    const int cpx = nwg >> 3;
    const int bid = (blockIdx.x & 7) * cpx + (blockIdx.x >> 3);

    const int qtile = bid & 15;
    const int b = (bid >> 4) & 7;
    const int ks = bid >> 7;

    const int qbase = qtile * 256 + w * 64;

    bf16x8 qfA = {}, qfB = {};
    if (h == 0) {
        qfA = *(const bf16x8*)(qw + ((size_t)b * NN + qbase + q) * 8);
        qfB = *(const bf16x8*)(qw + ((size_t)b * NN + qbase + 32 + q) * 8);
    }

    f32x16 accA0 = {}, accA1 = {}, accB0 = {}, accB1 = {};
    float lsumA = 0.f, lsumB = 0.f;

    const int NT = NN / KS / 64;
    const unsigned short* kb = kfrag + (size_t)b * 65536
                             + (size_t)ks * NT * 1024 + (size_t)lane * 8;
    const unsigned short* vbp = vfrag + (size_t)b * 262144
                              + (size_t)ks * NT * 4096 + (size_t)lane * 8;

    // one 32-key phase: QK scores already computed (sA,sB); consume 4 V slabs
    auto phase = [&](const f32x16& sA, const f32x16& sB,
                     bf16x8 va, bf16x8 vb2, bf16x8 vc, bf16x8 vd) {
        float pa[16], pb[16];
        #pragma unroll
        for (int r = 0; r < 16; ++r) { pa[r] = fast_exp2(sA[r]); pb[r] = fast_exp2(sB[r]); }
        {
            float a0 = 0.f, a1 = 0.f, b0 = 0.f, b1 = 0.f;
            #pragma unroll
            for (int r = 0; r < 8; ++r) {
                a0 += pa[r]; a1 += pa[8 + r];
                b0 += pb[r]; b1 += pb[8 + r];
            }
            lsumA += a0 + a1;
            lsumB += b0 + b1;
        }
        unsigned ka[8], kb2[8];
        #pragma unroll
        for (int j = 0; j < 8; ++j) {
            ka[j]  = cvt_pk_bf16(pa[2 * j], pa[2 * j + 1]);
            kb2[j] = cvt_pk_bf16(pb[2 * j], pb[2 * j + 1]);
        }
        __builtin_amdgcn_s_setprio(1);
        #pragma unroll
        for (int g2 = 0; g2 < 2; ++g2) {
            const unsigned* pga = &ka[4 * g2];
            auto ra = __builtin_amdgcn_permlane32_swap(pga[2], pga[0], false, false);
            auto rb = __builtin_amdgcn_permlane32_swap(pga[3], pga[1], false, false);
            uint4v bua = { ra[1], rb[1], ra[0], rb[0] };
            bf16x8 pfA = __builtin_bit_cast(bf16x8, bua);
            const unsigned* pgb = &kb2[4 * g2];
            auto rc = __builtin_amdgcn_permlane32_swap(pgb[2], pgb[0], false, false);
            auto rd = __builtin_amdgcn_permlane32_swap(pgb[3], pgb[1], false, false);
            uint4v bub = { rc[1], rd[1], rc[0], rd[0] };
            bf16x8 pfB = __builtin_bit_cast(bf16x8, bub);

            bf16x8 vx = g2 ? vc : va;
            bf16x8 vy = g2 ? vd : vb2;
            accA0 = __builtin_amdgcn_mfma_f32_32x32x16_bf16(vx, pfA, accA0, 0, 0, 0);
            accA1 = __builtin_amdgcn_mfma_f32_32x32x16_bf16(vy, pfA, accA1, 0, 0, 0);
            accB0 = __builtin_amdgcn_mfma_f32_32x32x16_bf16(vx, pfB, accB0, 0, 0, 0);
            accB1 = __builtin_amdgcn_mfma_f32_32x32x16_bf16(vy, pfB, accB1, 0, 0, 0);
        }
        __builtin_amdgcn_s_setprio(0);
    };

    bf16x8 kc0 = *(const bf16x8*)kb;
    bf16x8 kc1 = *(const bf16x8*)(kb + 512);

    for (int it = 0; it < NT; ++it) {
        const unsigned short* vp = vbp + (size_t)it * 4096;
        bf16x8 v0 = *(const bf16x8*)(vp);
        bf16x8 v1 = *(const bf16x8*)(vp + 512);
        bf16x8 v2 = *(const bf16x8*)(vp + 1024);
        bf16x8 v3 = *(const bf16x8*)(vp + 1536);
        bf16x8 v4 = *(const bf16x8*)(vp + 2048);
        bf16x8 v5 = *(const bf16x8*)(vp + 2560);
        bf16x8 v6 = *(const bf16x8*)(vp + 3072);
        bf16x8 v7 = *(const bf16x8*)(vp + 3584);

        const int nit = (it + 1 < NT) ? it + 1 : it;   // clamped, branchless
        const unsigned short* knp = kb + (size_t)nit * 1024;
        bf16x8 kn0 = *(const bf16x8*)knp;
        bf16x8 kn1 = *(const bf16x8*)(knp + 512);

        // phase 0: keys 0..31 of the tile
        {
            f32x16 sA = __builtin_amdgcn_mfma_f32_32x32x16_bf16(kc0, qfA, (f32x16){}, 0, 0, 0);
            f32x16 sB = __builtin_amdgcn_mfma_f32_32x32x16_bf16(kc0, qfB, (f32x16){}, 0, 0, 0);
            phase(sA, sB, v0, v1, v2, v3);
        }
        // phase 1: keys 32..63
        {
            f32x16 sA = __builtin_amdgcn_mfma_f32_32x32x16_bf16(kc1, qfA, (f32x16){}, 0, 0, 0);
            f32x16 sB = __builtin_amdgcn_mfma_f32_32x32x16_bf16(kc1, qfB, (f32x16){}, 0, 0, 0);
            phase(sA, sB, v4, v5, v6, v7);
        }
        kc0 = kn0;
        kc1 = kn1;
    }

    auto rsA = __builtin_amdgcn_permlane32_swap(__builtin_bit_cast(unsigned, lsumA),
                                                __builtin_bit_cast(unsigned, lsumA), false, false);
    float ltotA = __builtin_bit_cast(float, rsA[0]) + __builtin_bit_cast(float, rsA[1]);
    auto rsB = __builtin_amdgcn_permlane32_swap(__builtin_bit_cast(unsigned, lsumB),
                                                __builtin_bit_cast(unsigned, lsumB), false, false);
    float ltotB = __builtin_bit_cast(float, rsB[0]) + __builtin_bit_cast(float, rsB[1]);

    const float gm = FUSE ? gamma[0] : 0.f;

    #pragma unroll
    for (int sub = 0; sub < 2; ++sub) {
        const int n = qbase + sub * 32 + q;
        const float ltot = sub ? ltotB : ltotA;
        const f32x16& a0 = sub ? accB0 : accA0;
        const f32x16& a1 = sub ? accB1 : accA1;
        if (FUSE) {
            const float inv = 1.f / ltot;
            #pragma unroll
            for (int ct = 0; ct < 2; ++ct) {
                const f32x16& a = ct ? a1 : a0;
                #pragma unroll
                for (int r = 0; r < 16; ++r) {
                    int c = ct * 32 + (r & 3) + 8 * (r >> 2) + 4 * h;
                    size_t idx = ((size_t)(b * CC + c)) * NN + n;
                    out[idx] = X[idx] + gm * a[r] * inv;
                }
            }
        } else {
            unsigned short* po = pout + (size_t)ks * BB * CC * NN;
            #pragma unroll
            for (int ct = 0; ct < 2; ++ct) {
                const f32x16& a = ct ? a1 : a0;
                #pragma unroll
                for (int r = 0; r < 16; ++r) {
                    int c = ct * 32 + (r & 3) + 8 * (r >> 2) + 4 * h;
                    po[((size_t)(b * CC + c)) * NN + n] =
                        __builtin_bit_cast(unsigned short, __float2bfloat16(a[r]));
                }
            }
            if (h == 0) pl[((size_t)(ks * BB + b)) * NN + n] = ltot;
        }
    }
}

// ---------------------------------------------------------------------------
// Kernel 3: combine KS key-splits (bf16 partials) + epilogue.
// ---------------------------------------------------------------------------
template<int KS>
__global__ __launch_bounds__(256) void combine_kernel(
    const unsigned short* __restrict__ pout, const float* __restrict__ pl,
    const float* __restrict__ X, const float* __restrict__ gamma,
    float* __restrict__ out)
{
    const int idx = blockIdx.x * 256 + threadIdx.x;
    const int n4 = idx & 1023;
    const int c  = (idx >> 10) & 63;
    const int b  = idx >> 16;
    const int n0 = n4 * 4;
    const float gm = gamma[0];
    const size_t base = ((size_t)(b * CC + c)) * NN + n0;

    float4 s = make_float4(0.f, 0.f, 0.f, 0.f);
    float4 L = make_float4(0.f, 0.f, 0.f, 0.f);
    #pragma unroll
    for (int ks = 0; ks < KS; ++ks) {
        ushort4 sv = *(const ushort4*)(pout + (size_t)ks * BB * CC * NN + base);
        float4 lv = *(const float4*)(pl + ((size_t)(ks * BB + b)) * NN + n0);
        s.x += __bfloat162float(__builtin_bit_cast(__hip_bfloat16, sv.x));
        s.y += __bfloat162float(__builtin_bit_cast(__hip_bfloat16, sv.y));
        s.z += __bfloat162float(__builtin_bit_cast(__hip_bfloat16, sv.z));
        s.w += __bfloat162float(__builtin_bit_cast(__hip_bfloat16, sv.w));
        L.x += lv.x; L.y += lv.y; L.z += lv.z; L.w += lv.w;
    }
    float4 x = *(const float4*)(X + base);
    float4 o;
    o.x = x.x + gm * s.x / L.x;
    o.y = x.y + gm * s.y / L.y;
    o.z = x.z + gm * s.z / L.z;
    o.w = x.w + gm * s.w / L.w;
    *(float4*)(out + base) = o;
}

// ---------------------------------------------------------------------------
extern "C" void kernel_launch(void* const* d_in, const int* in_sizes, int n_in,
                              void* d_out, int out_size, void* d_ws, size_t ws_size,
                              hipStream_t stream) {
    const float* X  = (const float*)d_in[0];
    const float* Wq = (const float*)d_in[1];
    const float* bq = (const float*)d_in[2];
    const float* Wk = (const float*)d_in[3];
    const float* bk = (const float*)d_in[4];
    const float* Wv = (const float*)d_in[5];
    const float* bv = (const float*)d_in[6];
    const float* gm = (const float*)d_in[7];
    float* out = (float*)d_out;

    unsigned short* qw    = (unsigned short*)d_ws;
    unsigned short* kfrag = qw + (size_t)BB * NN * 8;
    unsigned short* vfrag = kfrag + (size_t)BB * 128 * 512;
    unsigned short* pout  = vfrag + (size_t)BB * 64 * 4096;
    float* pl = (float*)(pout + (size_t)4 * BB * CC * NN);

    const size_t qkv_bytes = ((size_t)BB * NN * 8 + (size_t)BB * 128 * 512
                            + (size_t)BB * 64 * 4096) * 2;
    const size_t need4 = qkv_bytes + (size_t)4 * BB * CC * NN * 2 + (size_t)4 * BB * NN * 4;
    const size_t need2 = qkv_bytes + (size_t)2 * BB * CC * NN * 2 + (size_t)2 * BB * NN * 4;

    qkv_kernel<<<dim3(640), dim3(256), 0, stream>>>(X, Wq, bq, Wk, bk, Wv, bv, qw, kfrag, vfrag);

    if (ws_size >= need4) {
        attn_kernel<4, false><<<dim3(512), dim3(256), 0, stream>>>(
            qw, kfrag, vfrag, pout, pl, X, gm, out);
        combine_kernel<4><<<dim3((BB * CC * NN / 4) / 256), dim3(256), 0, stream>>>(
            pout, pl, X, gm, out);
    } else if (ws_size >= need2) {
        float* pl2 = (float*)(pout + (size_t)2 * BB * CC * NN);
        attn_kernel<2, false><<<dim3(256), dim3(256), 0, stream>>>(
            qw, kfrag, vfrag, pout, pl2, X, gm, out);
        combine_kernel<2><<<dim3((BB * CC * NN / 4) / 256), dim3(256), 0, stream>>>(
            pout, pl2, X, gm, out);
    } else {
        attn_kernel<1, true><<<dim3(128), dim3(256), 0, stream>>>(
            qw, kfrag, vfrag, nullptr, nullptr, X, gm, out);
    }
}